// Round 1
// baseline (112.640 us; speedup 1.0000x reference)
//
#include <hip/hip_runtime.h>

// GAT layer, N=8192, IN_F=128, OUT_F=64.
//   Wh = h@W; Wh1 = Wh@a1; Wh2 = Wh@a2
//   e[i][j] = leakyrelu(Wh1[i]+Wh2[j]); p = adj>0 ? exp(e) : 0   (no max-sub:
//     scores bounded ~|8| << 88, fp32 exp safe; softmax == p/rowsum(p))
//   out = (P @ Wh) / rowsum
// Memory floor: adj read = 256 MB. PV done with bf16 MFMA 16x16x32, with P
// computed in-register directly in the A-fragment layout.

#define NN    8192
#define INF   128
#define OUTF  64
#define BM    32      // rows per block (kernel2)
#define JSPLIT 4      // j-dimension split across blocks
#define CHUNK 32      // j per MFMA K-step
#define ALPHAS 0.2f

typedef float  f32x4 __attribute__((ext_vector_type(4)));
typedef int    i32x4 __attribute__((ext_vector_type(4)));
typedef short  s16x8 __attribute__((ext_vector_type(8)));
typedef __bf16 bf16x8 __attribute__((ext_vector_type(8)));

__device__ __forceinline__ unsigned short f2bf(float x) {
    // round-to-nearest-even f32 -> bf16 bits (inputs here are finite, >= 0)
    unsigned u = __builtin_bit_cast(unsigned, x);
    return (unsigned short)((u + 0x7fffu + ((u >> 16) & 1u)) >> 16);
}

// ---------------- kernel 1: Wh, Wh1, Wh2, packed bf16 Wh (B-fragment order)
// packed layout: whbp[jc][nb][lane][jj], jc=j>>5, nb=col>>4,
//   lane = ((j&31)>>3)*16 + (col&15), jj = j&7  -> element Whb[j][col]
__global__ __launch_bounds__(256) void gat_prep(
    const float* __restrict__ h, const float* __restrict__ W,
    const float* __restrict__ a, float* __restrict__ wh1,
    float* __restrict__ wh2, unsigned short* __restrict__ whbp)
{
    __shared__ float sW[INF * OUTF];   // 32 KB
    __shared__ float sA[2 * OUTF];
    __shared__ float sH[4][INF];
    const int tid = threadIdx.x, lane = tid & 63, wid = tid >> 6;

    for (int idx = tid; idx < INF * OUTF; idx += 256) sW[idx] = W[idx];
    if (tid < 2 * OUTF) sA[tid] = a[tid];
    __syncthreads();

    const int nw = gridDim.x * 4;
    for (int r = blockIdx.x * 4 + wid; r < NN; r += nw) {
        sH[wid][lane]      = h[(size_t)r * INF + lane];
        sH[wid][64 + lane] = h[(size_t)r * INF + 64 + lane];
        float acc = 0.f;
        #pragma unroll 8
        for (int k = 0; k < INF; ++k)
            acc = fmaf(sH[wid][k], sW[k * OUTF + lane], acc);
        // Wh1/Wh2 wave reductions
        float v1 = acc * sA[lane];
        float v2 = acc * sA[64 + lane];
        #pragma unroll
        for (int off = 32; off; off >>= 1) {
            v1 += __shfl_xor(v1, off);
            v2 += __shfl_xor(v2, off);
        }
        if (lane == 0) { wh1[r] = v1; wh2[r] = v2; }
        // packed bf16 write (scattered ushort, tiny total: 1 MB)
        int jc = r >> 5, nb = lane >> 4;
        int lp = (((r & 31) >> 3) << 4) | (lane & 15);
        int jj = r & 7;
        whbp[(size_t)jc * 2048 + nb * 512 + lp * 8 + jj] = f2bf(acc);
    }
}

// ---------------- kernel 2: main pass, streams adj, accumulates partials
__global__ __launch_bounds__(256, 4) void gat_main(
    const int* __restrict__ adj, const float* __restrict__ wh1,
    const float* __restrict__ wh2, const unsigned short* __restrict__ whbp,
    float* __restrict__ accP, float* __restrict__ lP)
{
    __shared__ float sAcc[4][16 * 64];  // 16 KB
    __shared__ float sL[4][16];
    const int tid = threadIdx.x, lane = tid & 63, wid = tid >> 6;
    const int rowhalf = wid >> 1, jpar = wid & 1;
    const int rb = blockIdx.x >> 2, js = blockIdx.x & 3;
    const int row  = rb * BM + rowhalf * 16 + (lane & 15);
    const int klo  = lane >> 4;            // 0..3 -> k-slot base klo*8
    const float wh1v = wh1[row];
    const int* adjrow = adj + (size_t)row * NN;

    f32x4 acc0 = {0.f,0.f,0.f,0.f}, acc1 = acc0, acc2 = acc0, acc3 = acc0;
    float rowsum = 0.f;

    const int nchunks = (NN / JSPLIT) / CHUNK;   // 64
    for (int t = jpar; t < nchunks; t += 2) {
        const int jb = js * (NN / JSPLIT) + t * CHUNK;
        const int j0 = jb + klo * 8;
        i32x4 ad0 = __builtin_nontemporal_load((const i32x4*)(adjrow + j0));
        i32x4 ad1 = __builtin_nontemporal_load((const i32x4*)(adjrow + j0 + 4));
        f32x4 w20 = *(const f32x4*)(wh2 + j0);
        f32x4 w21 = *(const f32x4*)(wh2 + j0 + 4);
        const unsigned short* bp = whbp + (size_t)(jb >> 5) * 2048 + lane * 8;
        bf16x8 b0 = *(const bf16x8*)(bp);
        bf16x8 b1 = *(const bf16x8*)(bp + 512);
        bf16x8 b2 = *(const bf16x8*)(bp + 1024);
        bf16x8 b3 = *(const bf16x8*)(bp + 1536);

        s16x8 pa;
        #pragma unroll
        for (int u = 0; u < 4; ++u) {
            float tt = wh1v + w20[u];
            float e  = fmaxf(tt, ALPHAS * tt);          // leaky_relu
            float p  = (ad0[u] > 0) ? __expf(e) : 0.f;  // mask -> exp(-inf)=0
            rowsum += p;
            pa[u] = (short)f2bf(p);
        }
        #pragma unroll
        for (int u = 0; u < 4; ++u) {
            float tt = wh1v + w21[u];
            float e  = fmaxf(tt, ALPHAS * tt);
            float p  = (ad1[u] > 0) ? __expf(e) : 0.f;
            rowsum += p;
            pa[4 + u] = (short)f2bf(p);
        }
        bf16x8 af = __builtin_bit_cast(bf16x8, pa);
        acc0 = __builtin_amdgcn_mfma_f32_16x16x32_bf16(af, b0, acc0, 0, 0, 0);
        acc1 = __builtin_amdgcn_mfma_f32_16x16x32_bf16(af, b1, acc1, 0, 0, 0);
        acc2 = __builtin_amdgcn_mfma_f32_16x16x32_bf16(af, b2, acc2, 0, 0, 0);
        acc3 = __builtin_amdgcn_mfma_f32_16x16x32_bf16(af, b3, acc3, 0, 0, 0);
    }

    // rowsum: combine the 4 k-slot lane groups (lanes with equal lane&15)
    rowsum += __shfl_xor(rowsum, 16);
    rowsum += __shfl_xor(rowsum, 32);
    if (lane < 16) sL[wid][lane] = rowsum;

    // spill acc to LDS (C/D layout: row=(lane>>4)*4+r, col=nb*16+(lane&15))
    #pragma unroll
    for (int r = 0; r < 4; ++r) {
        int lrow = klo * 4 + r;
        sAcc[wid][lrow * 64 +  0 + (lane & 15)] = acc0[r];
        sAcc[wid][lrow * 64 + 16 + (lane & 15)] = acc1[r];
        sAcc[wid][lrow * 64 + 32 + (lane & 15)] = acc2[r];
        sAcc[wid][lrow * 64 + 48 + (lane & 15)] = acc3[r];
    }
    __syncthreads();

    // combine jpar 0/1 wave pairs, write per-(rowblock, js) partials
    for (int idx = tid; idx < BM * 64; idx += 256) {
        int r = idx >> 6, c = idx & 63;
        int rh = r >> 4;
        float v = sAcc[2 * rh][(r & 15) * 64 + c] + sAcc[2 * rh + 1][(r & 15) * 64 + c];
        accP[(size_t)js * (NN * OUTF) + (size_t)(rb * BM + r) * OUTF + c] = v;
    }
    if (tid < BM) {
        int rh = tid >> 4;
        lP[(size_t)js * NN + rb * BM + tid] =
            sL[2 * rh][tid & 15] + sL[2 * rh + 1][tid & 15];
    }
}

// ---------------- kernel 3: reduce JSPLIT partials, divide
__global__ __launch_bounds__(256) void gat_final(
    const float* __restrict__ accP, const float* __restrict__ lP,
    float* __restrict__ out)
{
    int idx = blockIdx.x * 256 + threadIdx.x;   // i*64 + c
    int i = idx >> 6;
    float s = 0.f, l = 0.f;
    #pragma unroll
    for (int js = 0; js < JSPLIT; ++js) {
        s += accP[(size_t)js * (NN * OUTF) + idx];
        l += lP[(size_t)js * NN + i];
    }
    out[idx] = s / l;
}

extern "C" void kernel_launch(void* const* d_in, const int* in_sizes, int n_in,
                              void* d_out, int out_size, void* d_ws, size_t ws_size,
                              hipStream_t stream) {
    const float* h   = (const float*)d_in[0];
    const float* W   = (const float*)d_in[1];
    const float* a   = (const float*)d_in[2];
    const int*   adj = (const int*)d_in[3];
    float* out = (float*)d_out;

    char* ws = (char*)d_ws;
    unsigned short* whbp = (unsigned short*)ws;                       // 1 MB
    float* wh1  = (float*)(ws + (1u << 20));                          // 32 KB
    float* wh2  = (float*)(ws + (1u << 20) + 32768);                  // 32 KB
    float* accP = (float*)(ws + (1u << 20) + 65536);                  // 8 MB
    float* lP   = (float*)(ws + (1u << 20) + 65536 +
                           (size_t)JSPLIT * NN * OUTF * 4);           // 128 KB

    gat_prep<<<512, 256, 0, stream>>>(h, W, a, wh1, wh2, whbp);
    gat_main<<<(NN / BM) * JSPLIT, 256, 0, stream>>>(adj, wh1, wh2, whbp, accP, lP);
    gat_final<<<(NN * OUTF) / 256, 256, 0, stream>>>(accP, lP, out);
}

// Round 2
// 105.382 us; speedup vs baseline: 1.0689x; 1.0689x over previous
//
#include <hip/hip_runtime.h>

// GAT layer, N=8192, IN_F=128, OUT_F=64.
//   Wh = h@W; Wh1 = Wh@a1; Wh2 = Wh@a2
//   e[i][j] = leakyrelu(Wh1[i]+Wh2[j]); p = adj>0 ? exp(e) : 0
//   out = (P @ Wh) / rowsum(P)
// No max-subtraction needed: |scores| <~ 8 << 88, fp32 exp safe.
// Roofline floor: adj read = 256 MB => ~40 us @ 6.5 TB/s.
// Round 2: JSPLIT=1 (one block owns 32 full rows => sequential-per-row adj
// streaming, 8K streams instead of 32K), fused divide (no partials kernel),
// exp2-domain scores (wh1/wh2 pre-scaled by log2e in prep).

#define NN    8192
#define INF   128
#define OUTF  64
#define BM    32      // rows per block (kernel2)
#define CHUNK 32      // j per MFMA K-step
#define LOG2E 1.4426950408889634f

typedef float  f32x4 __attribute__((ext_vector_type(4)));
typedef int    i32x4 __attribute__((ext_vector_type(4)));
typedef __bf16 bf16x8 __attribute__((ext_vector_type(8)));

__device__ __forceinline__ unsigned short f2bf(float x) {
    unsigned u = __builtin_bit_cast(unsigned, x);
    return (unsigned short)((u + 0x7fffu + ((u >> 16) & 1u)) >> 16);
}

// ---------------- kernel 1: Wh, scaled Wh1/Wh2, packed bf16 Wh (B-frag order)
// packed layout: whbp[jc][nb][lane][jj]: element Wh[j][col] with
//   j = jc*32 + (lane>>4)*8 + jj, col = nb*16 + (lane&15)
__global__ __launch_bounds__(256) void gat_prep(
    const float* __restrict__ h, const float* __restrict__ W,
    const float* __restrict__ a, float* __restrict__ wh1s,
    float* __restrict__ wh2s, unsigned short* __restrict__ whbp)
{
    __shared__ float sW[INF * OUTF];   // 32 KB
    __shared__ float sA[2 * OUTF];
    __shared__ float sH[4][INF];
    const int tid = threadIdx.x, lane = tid & 63, wid = tid >> 6;

    for (int idx = tid; idx < INF * OUTF; idx += 256) sW[idx] = W[idx];
    if (tid < 2 * OUTF) sA[tid] = a[tid];
    __syncthreads();

    const int nw = gridDim.x * 4;
    for (int r = blockIdx.x * 4 + wid; r < NN; r += nw) {
        sH[wid][lane]      = h[(size_t)r * INF + lane];
        sH[wid][64 + lane] = h[(size_t)r * INF + 64 + lane];
        float acc = 0.f;
        #pragma unroll 8
        for (int k = 0; k < INF; ++k)
            acc = fmaf(sH[wid][k], sW[k * OUTF + lane], acc);
        float v1 = acc * sA[lane];
        float v2 = acc * sA[64 + lane];
        #pragma unroll
        for (int off = 32; off; off >>= 1) {
            v1 += __shfl_xor(v1, off);
            v2 += __shfl_xor(v2, off);
        }
        if (lane == 0) { wh1s[r] = v1 * LOG2E; wh2s[r] = v2 * LOG2E; }
        int jc = r >> 5, nb = lane >> 4;
        int lp = (((r & 31) >> 3) << 4) | (lane & 15);
        int jj = r & 7;
        whbp[(size_t)jc * 2048 + nb * 512 + lp * 8 + jj] = f2bf(acc);
    }
}

// ---------------- kernel 2: stream adj, fused softmax-normalized PV out
// 256 blocks x 1024 thr (16 waves = 2 rowhalves x 8 j-interleaved waves)
__global__ __launch_bounds__(1024, 4) void gat_main(
    const int* __restrict__ adj, const float* __restrict__ wh1s,
    const float* __restrict__ wh2s, const unsigned short* __restrict__ whbp,
    float* __restrict__ out)
{
    __shared__ float sAcc[16][16 * 64];  // 64 KB
    __shared__ float sL[16][16];
    const int tid = threadIdx.x, lane = tid & 63, wid = tid >> 6;
    const int rowhalf = wid >> 3, jpar = wid & 7;
    const int rb = blockIdx.x;
    const int r16 = lane & 15;
    const int row = rb * BM + rowhalf * 16 + r16;
    const int klo = lane >> 4;              // k-slot group 0..3
    const float wh1v = wh1s[row];
    const int* adjrow = adj + (size_t)row * NN;

    f32x4 acc0 = {0.f,0.f,0.f,0.f}, acc1 = acc0, acc2 = acc0, acc3 = acc0;
    float rs0 = 0.f, rs1 = 0.f;

    const int nch = NN / CHUNK;             // 256
    for (int t = jpar; t < nch; t += 8) {
        const int j0 = t * CHUNK + klo * 8;
        i32x4 ad0 = __builtin_nontemporal_load((const i32x4*)(adjrow + j0));
        i32x4 ad1 = __builtin_nontemporal_load((const i32x4*)(adjrow + j0 + 4));
        f32x4 w20 = *(const f32x4*)(wh2s + j0);
        f32x4 w21 = *(const f32x4*)(wh2s + j0 + 4);
        const unsigned short* bp = whbp + (size_t)t * 2048 + lane * 8;
        bf16x8 b0 = *(const bf16x8*)(bp);
        bf16x8 b1 = *(const bf16x8*)(bp + 512);
        bf16x8 b2 = *(const bf16x8*)(bp + 1024);
        bf16x8 b3 = *(const bf16x8*)(bp + 1536);

        bf16x8 af;
        #pragma unroll
        for (int u = 0; u < 4; ++u) {
            float tt = wh1v + w20[u];
            float e  = fmaxf(tt, 0.2f * tt);                 // leaky (log2 dom.)
            float p  = (ad0[u] > 0) ? __builtin_amdgcn_exp2f(e) : 0.f;
            rs0 += p;
            af[u] = (__bf16)p;
        }
        #pragma unroll
        for (int u = 0; u < 4; ++u) {
            float tt = wh1v + w21[u];
            float e  = fmaxf(tt, 0.2f * tt);
            float p  = (ad1[u] > 0) ? __builtin_amdgcn_exp2f(e) : 0.f;
            rs1 += p;
            af[4 + u] = (__bf16)p;
        }
        acc0 = __builtin_amdgcn_mfma_f32_16x16x32_bf16(af, b0, acc0, 0, 0, 0);
        acc1 = __builtin_amdgcn_mfma_f32_16x16x32_bf16(af, b1, acc1, 0, 0, 0);
        acc2 = __builtin_amdgcn_mfma_f32_16x16x32_bf16(af, b2, acc2, 0, 0, 0);
        acc3 = __builtin_amdgcn_mfma_f32_16x16x32_bf16(af, b3, acc3, 0, 0, 0);
    }

    float rowsum = rs0 + rs1;
    rowsum += __shfl_xor(rowsum, 16);
    rowsum += __shfl_xor(rowsum, 32);
    if (lane < 16) sL[wid][lane] = rowsum;

    // C/D layout: row = klo*4 + r, col = nb*16 + (lane&15)
    #pragma unroll
    for (int r = 0; r < 4; ++r) {
        int lrow = klo * 4 + r;
        sAcc[wid][lrow * 64 +  0 + r16] = acc0[r];
        sAcc[wid][lrow * 64 + 16 + r16] = acc1[r];
        sAcc[wid][lrow * 64 + 32 + r16] = acc2[r];
        sAcc[wid][lrow * 64 + 48 + r16] = acc3[r];
    }
    __syncthreads();

    // combine the 8 j-waves per rowhalf, divide by rowsum, write out
    for (int idx = tid; idx < BM * OUTF; idx += 1024) {
        int r = idx >> 6, c = idx & 63;
        int rh = r >> 4;
        float s = 0.f, l = 0.f;
        #pragma unroll
        for (int w = 0; w < 8; ++w) {
            s += sAcc[rh * 8 + w][(r & 15) * 64 + c];
            l += sL[rh * 8 + w][r & 15];
        }
        out[(size_t)(rb * BM + r) * OUTF + c] = s / l;
    }
}

extern "C" void kernel_launch(void* const* d_in, const int* in_sizes, int n_in,
                              void* d_out, int out_size, void* d_ws, size_t ws_size,
                              hipStream_t stream) {
    const float* h   = (const float*)d_in[0];
    const float* W   = (const float*)d_in[1];
    const float* a   = (const float*)d_in[2];
    const int*   adj = (const int*)d_in[3];
    float* out = (float*)d_out;

    char* ws = (char*)d_ws;
    unsigned short* whbp = (unsigned short*)ws;             // 1 MB
    float* wh1s = (float*)(ws + (1u << 20));                // 32 KB
    float* wh2s = (float*)(ws + (1u << 20) + 32768);        // 32 KB

    gat_prep<<<512, 256, 0, stream>>>(h, W, a, wh1s, wh2s, whbp);
    gat_main<<<NN / BM, 1024, 0, stream>>>(adj, wh1s, wh2s, whbp, out);
}

// Round 3
// 79.183 us; speedup vs baseline: 1.4225x; 1.3309x over previous
//
#include <hip/hip_runtime.h>

// GAT layer, N=8192, IN_F=128, OUT_F=64.
//   Wh = h@W; Wh1 = Wh@a1; Wh2 = Wh@a2
//   e[i][j] = leakyrelu(Wh1[i]+Wh2[j]); p = adj>0 ? exp(e) : 0
//   out = (P @ Wh) / rowsum(P)
// Floor: adj read = 256 MB => ~40 us @ 6.3 TB/s.
// Round 3: fully-coalesced adj reads (1 KB/instr, one row per instr) with
// P staged through XOR-swizzled LDS into MFMA fragment order; adj prefetch
// for round r+1 issued AFTER B-frag loads so counted vmcnt keeps it in
// flight across the MFMA phase.

#define NN    8192
#define INF   128
#define OUTF  64
#define BM    32       // rows per block
#define RJ    512      // j per round
#define NR    (NN/RJ)  // 16 rounds
#define LOG2E 1.4426950408889634f

typedef float  f32x4 __attribute__((ext_vector_type(4)));
typedef int    i32x4 __attribute__((ext_vector_type(4)));
typedef __bf16 bf16x4 __attribute__((ext_vector_type(4)));
typedef __bf16 bf16x8 __attribute__((ext_vector_type(8)));

__device__ __forceinline__ unsigned short f2bf(float x) {
    unsigned u = __builtin_bit_cast(unsigned, x);
    return (unsigned short)((u + 0x7fffu + ((u >> 16) & 1u)) >> 16);
}

// ---------------- kernel 1: Wh, scaled Wh1/Wh2, packed bf16 Wh (B-frag order)
// whbp element Wh[j][col]: chunk jc=j>>5, addr jc*2048 + nb*512 + lp*8 + jj,
//   nb=col>>4, lp=((j&31)>>3)*16 + (col&15), jj=j&7
__global__ __launch_bounds__(256) void gat_prep(
    const float* __restrict__ h, const float* __restrict__ W,
    const float* __restrict__ a, float* __restrict__ wh1s,
    float* __restrict__ wh2s, unsigned short* __restrict__ whbp)
{
    __shared__ float sW[INF * OUTF];   // 32 KB
    __shared__ float sA[2 * OUTF];
    __shared__ float sH[4][INF];
    const int tid = threadIdx.x, lane = tid & 63, wid = tid >> 6;

    for (int idx = tid; idx < INF * OUTF; idx += 256) sW[idx] = W[idx];
    if (tid < 2 * OUTF) sA[tid] = a[tid];
    __syncthreads();

    const int nw = gridDim.x * 4;
    for (int r = blockIdx.x * 4 + wid; r < NN; r += nw) {
        sH[wid][lane]      = h[(size_t)r * INF + lane];
        sH[wid][64 + lane] = h[(size_t)r * INF + 64 + lane];
        float acc = 0.f;
        #pragma unroll 8
        for (int k = 0; k < INF; ++k)
            acc = fmaf(sH[wid][k], sW[k * OUTF + lane], acc);
        float v1 = acc * sA[lane];
        float v2 = acc * sA[64 + lane];
        #pragma unroll
        for (int off = 32; off; off >>= 1) {
            v1 += __shfl_xor(v1, off);
            v2 += __shfl_xor(v2, off);
        }
        if (lane == 0) { wh1s[r] = v1 * LOG2E; wh2s[r] = v2 * LOG2E; }
        int jc = r >> 5, nb = lane >> 4;
        int lp = (((r & 31) >> 3) << 4) | (lane & 15);
        int jj = r & 7;
        whbp[(size_t)jc * 2048 + nb * 512 + lp * 8 + jj] = f2bf(acc);
    }
}

// ---------------- kernel 2: coalesced adj stream -> swizzled LDS P -> MFMA
// 256 blocks x 1024 threads (16 waves). Phase A: wave w owns rows 2w,2w+1.
// Phase B: wave w = (rh = w>>3, js = w&7) does j-slice js*64..+63 per round.
__global__ __launch_bounds__(1024, 4) void gat_main(
    const int* __restrict__ adj, const float* __restrict__ wh1s,
    const float* __restrict__ wh2s, const unsigned short* __restrict__ whbp,
    float* __restrict__ out)
{
    __shared__ __align__(16) char smem[2 * BM * RJ * 2];  // 64 KB: P dbuf / sAcc alias
    __shared__ float sRow[BM];

    const int tid = threadIdx.x, lane = tid & 63, wid = tid >> 6;
    const int rb = blockIdx.x;
    const int r16 = lane & 15, klo = lane >> 4;

    // phase-A role
    const int ra0 = 2 * wid, ra1 = ra0 + 1;
    const int grow0 = rb * BM + ra0, grow1 = rb * BM + ra1;
    const float wh1v0 = wh1s[grow0], wh1v1 = wh1s[grow1];
    const int* adjr0 = adj + (size_t)grow0 * NN;
    const int* adjr1 = adj + (size_t)grow1 * NN;
    const int x0 = (ra0 & 7) << 4, x1 = (ra1 & 7) << 4;

    // phase-B role
    const int rh = wid >> 3, js = wid & 7;
    const int rloc = rh * 16 + r16;
    const int xr = (rloc & 7) << 4;

    f32x4 acc0 = {0.f,0.f,0.f,0.f}, acc1 = acc0, acc2 = acc0, acc3 = acc0;
    float rs0 = 0.f, rs1 = 0.f;

    i32x4 A00, A01, A10, A11;   // adj prefetch regs [row][seg]
    f32x4 W0, W1;               // wh2 prefetch regs [seg]

    auto LOAD = [&](int rr) {
        const int jb = rr * RJ + lane * 4;
        A00 = __builtin_nontemporal_load((const i32x4*)(adjr0 + jb));
        A01 = __builtin_nontemporal_load((const i32x4*)(adjr0 + jb + 256));
        A10 = __builtin_nontemporal_load((const i32x4*)(adjr1 + jb));
        A11 = __builtin_nontemporal_load((const i32x4*)(adjr1 + jb + 256));
        W0  = *(const f32x4*)(wh2s + jb);
        W1  = *(const f32x4*)(wh2s + jb + 256);
    };

    auto PROC = [&](i32x4 ad, f32x4 w2, float w1, float& rs) -> bf16x4 {
        bf16x4 o;
        #pragma unroll
        for (int u = 0; u < 4; ++u) {
            float tt = w1 + w2[u];
            float e  = fmaxf(tt, 0.2f * tt);             // leaky (log2 domain)
            float p  = (ad[u] > 0) ? __builtin_amdgcn_exp2f(e) : 0.f;
            rs += p;
            o[u] = (__bf16)p;
        }
        return o;
    };

    auto STORE = [&](int rr) {
        char* Pb = smem + ((rr & 1) << 15);
        bf16x4 p00 = PROC(A00, W0, wh1v0, rs0);
        bf16x4 p01 = PROC(A01, W1, wh1v0, rs0);
        bf16x4 p10 = PROC(A10, W0, wh1v1, rs1);
        bf16x4 p11 = PROC(A11, W1, wh1v1, rs1);
        *(bf16x4*)(Pb + ra0 * 1024 + (((lane * 8)      ) ^ x0)) = p00;
        *(bf16x4*)(Pb + ra0 * 1024 + (((lane * 8) + 512) ^ x0)) = p01;
        *(bf16x4*)(Pb + ra1 * 1024 + (((lane * 8)      ) ^ x1)) = p10;
        *(bf16x4*)(Pb + ra1 * 1024 + (((lane * 8) + 512) ^ x1)) = p11;
    };

    LOAD(0);
    for (int rr = 0; rr < NR; ++rr) {
        STORE(rr);                       // waits on adj regs (loaded last round)
        __syncthreads();                 // P[rr] visible to all waves

        const char* Pb = smem + ((rr & 1) << 15);
        const int jb = rr * RJ;

        // B-frag loads FIRST (so the adj prefetch issued after them stays
        // outstanding under counted vmcnt during the MFMA phase)
        bf16x8 B[2][4];
        #pragma unroll
        for (int kk = 0; kk < 2; ++kk) {
            const unsigned short* bp =
                whbp + (size_t)((jb + js * 64 + kk * 32) >> 5) * 2048 + lane * 8;
            B[kk][0] = *(const bf16x8*)(bp);
            B[kk][1] = *(const bf16x8*)(bp + 512);
            B[kk][2] = *(const bf16x8*)(bp + 1024);
            B[kk][3] = *(const bf16x8*)(bp + 1536);
        }
        if (rr + 1 < NR) LOAD(rr + 1);   // adj prefetch: issued last, waited next round

        #pragma unroll
        for (int kk = 0; kk < 2; ++kk) {
            const int jloc = js * 64 + kk * 32;
            bf16x8 af = *(const bf16x8*)(Pb + rloc * 1024 +
                                         (((jloc + klo * 8) * 2) ^ xr));
            acc0 = __builtin_amdgcn_mfma_f32_16x16x32_bf16(af, B[kk][0], acc0, 0, 0, 0);
            acc1 = __builtin_amdgcn_mfma_f32_16x16x32_bf16(af, B[kk][1], acc1, 0, 0, 0);
            acc2 = __builtin_amdgcn_mfma_f32_16x16x32_bf16(af, B[kk][2], acc2, 0, 0, 0);
            acc3 = __builtin_amdgcn_mfma_f32_16x16x32_bf16(af, B[kk][3], acc3, 0, 0, 0);
        }
    }
    __syncthreads();   // all P reads done; safe to alias smem as sAcc

    // per-row softmax denominators
    float r0 = rs0, r1 = rs1;
    #pragma unroll
    for (int off = 32; off; off >>= 1) {
        r0 += __shfl_xor(r0, off);
        r1 += __shfl_xor(r1, off);
    }
    if (lane == 0) { sRow[ra0] = r0; sRow[ra1] = r1; }

    // spill acc (C/D layout: row = klo*4 + r, col = nb*16 + r16)
    float* sAcc = (float*)smem;          // [16][1024]
    #pragma unroll
    for (int r = 0; r < 4; ++r) {
        int lrow = klo * 4 + r;
        sAcc[wid * 1024 + lrow * 64 +  0 + r16] = acc0[r];
        sAcc[wid * 1024 + lrow * 64 + 16 + r16] = acc1[r];
        sAcc[wid * 1024 + lrow * 64 + 32 + r16] = acc2[r];
        sAcc[wid * 1024 + lrow * 64 + 48 + r16] = acc3[r];
    }
    __syncthreads();

    // combine the 8 j-slice waves per rowhalf, divide, write out
    for (int idx = tid; idx < BM * OUTF; idx += 1024) {
        int r = idx >> 6, c = idx & 63, rhh = r >> 4;
        float s = 0.f;
        #pragma unroll
        for (int w = 0; w < 8; ++w)
            s += sAcc[(rhh * 8 + w) * 1024 + (r & 15) * 64 + c];
        out[(size_t)(rb * BM + r) * OUTF + c] = s / sRow[r];
    }
}

extern "C" void kernel_launch(void* const* d_in, const int* in_sizes, int n_in,
                              void* d_out, int out_size, void* d_ws, size_t ws_size,
                              hipStream_t stream) {
    const float* h   = (const float*)d_in[0];
    const float* W   = (const float*)d_in[1];
    const float* a   = (const float*)d_in[2];
    const int*   adj = (const int*)d_in[3];
    float* out = (float*)d_out;

    char* ws = (char*)d_ws;
    unsigned short* whbp = (unsigned short*)ws;             // 1 MB
    float* wh1s = (float*)(ws + (1u << 20));                // 32 KB
    float* wh2s = (float*)(ws + (1u << 20) + 32768);        // 32 KB

    gat_prep<<<512, 256, 0, stream>>>(h, W, a, wh1s, wh2s, whbp);
    gat_main<<<NN / BM, 1024, 0, stream>>>(adj, wh1s, wh2s, whbp, out);
}